// Round 1
// baseline (35.929 us; speedup 1.0000x reference)
//
#include <hip/hip_runtime.h>

// Problem: DiceLoss over input (B=16, C=4, H=512, W=512) f32, target (B,H,W) int.
// pred = argmax_c input; counts per class: #pred==c, #tgt==c, #(pred==c & tgt==c).
// loss = mean_c (1 - (2*inter+eps)/(pred_cnt+tgt_cnt+eps)).

static constexpr int kHW   = 512 * 512;     // 262144
static constexpr int kB    = 16;
static constexpr int kC    = 4;
static constexpr int kNPix = kB * kHW;      // 4194304
static constexpr float kEps = 1e-6f;

__global__ __launch_bounds__(256) void dice_count_kernel(
    const float* __restrict__ in, const int* __restrict__ tgt,
    unsigned int* __restrict__ cnt)
{
    unsigned int loc[12];
#pragma unroll
    for (int i = 0; i < 12; ++i) loc[i] = 0;

    const int nvec   = kNPix / 4;
    const int stride = gridDim.x * blockDim.x;
    for (int v = blockIdx.x * blockDim.x + threadIdx.x; v < nvec; v += stride) {
        const int p  = v << 2;          // first pixel of the quad
        const int b  = p >> 18;         // p / kHW
        const int hw = p & (kHW - 1);   // p % kHW
        const float* base = in + ((size_t)b * kC) * kHW + hw;
        const float4 c0 = *(const float4*)(base);
        const float4 c1 = *(const float4*)(base + kHW);
        const float4 c2 = *(const float4*)(base + 2 * kHW);
        const float4 c3 = *(const float4*)(base + 3 * kHW);
        const int4   t4 = *(const int4*)(tgt + p);

        const float a0[4] = {c0.x, c0.y, c0.z, c0.w};
        const float a1[4] = {c1.x, c1.y, c1.z, c1.w};
        const float a2[4] = {c2.x, c2.y, c2.z, c2.w};
        const float a3[4] = {c3.x, c3.y, c3.z, c3.w};
        const int   tv[4] = {t4.x, t4.y, t4.z, t4.w};

#pragma unroll
        for (int j = 0; j < 4; ++j) {
            // argmax with first-occurrence tie-break (strict >)
            int pred = 0; float bv = a0[j];
            if (a1[j] > bv) { bv = a1[j]; pred = 1; }
            if (a2[j] > bv) { bv = a2[j]; pred = 2; }
            if (a3[j] > bv) { bv = a3[j]; pred = 3; }
            const int t = tv[j];
#pragma unroll
            for (int c = 0; c < 4; ++c) {
                loc[c]     += (pred == c);
                loc[4 + c] += (t == c);
                loc[8 + c] += (unsigned)((pred == c) & (t == c));
            }
        }
    }

    // wave64 butterfly reduce each of the 12 counts
#pragma unroll
    for (int i = 0; i < 12; ++i) {
        unsigned int x = loc[i];
        for (int o = 32; o > 0; o >>= 1) x += __shfl_down(x, o, 64);
        loc[i] = x;
    }

    __shared__ unsigned int s[12];
    if (threadIdx.x < 12) s[threadIdx.x] = 0;
    __syncthreads();
    if ((threadIdx.x & 63) == 0) {
#pragma unroll
        for (int i = 0; i < 12; ++i) atomicAdd(&s[i], loc[i]);
    }
    __syncthreads();
    if (threadIdx.x < 12) atomicAdd(&cnt[threadIdx.x], s[threadIdx.x]);
}

__global__ void dice_final_kernel(const unsigned int* __restrict__ cnt,
                                  float* __restrict__ out)
{
    if (threadIdx.x == 0 && blockIdx.x == 0) {
        float loss = 0.0f;
#pragma unroll
        for (int c = 0; c < kC; ++c) {
            const float inter = (float)cnt[8 + c];
            const float uni   = (float)cnt[c] + (float)cnt[4 + c];
            const float dice  = (2.0f * inter + kEps) / (uni + kEps);
            loss += 1.0f - dice;
        }
        out[0] = loss * (1.0f / (float)kC);
    }
}

extern "C" void kernel_launch(void* const* d_in, const int* in_sizes, int n_in,
                              void* d_out, int out_size, void* d_ws, size_t ws_size,
                              hipStream_t stream) {
    const float* in  = (const float*)d_in[0];
    const int*   tgt = (const int*)d_in[1];   // harness passes integer inputs as int32
    float* out = (float*)d_out;
    unsigned int* cnt = (unsigned int*)d_ws;

    hipMemsetAsync(cnt, 0, 12 * sizeof(unsigned int), stream);
    dice_count_kernel<<<1024, 256, 0, stream>>>(in, tgt, cnt);
    dice_final_kernel<<<1, 64, 0, stream>>>(cnt, out);
}